// Round 2
// baseline (538.006 us; speedup 1.0000x reference)
//
#include <hip/hip_runtime.h>
#include <hip/hip_bf16.h>
#include <stdint.h>

#define NL 2048
#define NR 4096
#define NCHUNK 8
#define CHUNK (NR / NCHUNK) /* 512 */
#define SCALE 0.125f
#define LN_EPS 1e-5f

typedef __attribute__((ext_vector_type(8))) short short8;  // 8 bf16 in 4 VGPRs
typedef __attribute__((ext_vector_type(4))) float float4v;

static __device__ __forceinline__ short f2bf(float f) {
  union { float f; uint32_t u; } v; v.f = f;
  uint32_t u = v.u;
  uint32_t r = (u + 0x7FFFu + ((u >> 16) & 1u)) >> 16;  // RNE
  return (short)(r & 0xFFFFu);
}
static __device__ __forceinline__ float bf2f(short b) {
  union { uint32_t u; float f; } v; v.u = ((uint32_t)(uint16_t)b) << 16;
  return v.f;
}

// ---------------- K0: fp32 -> bf16 conversions -------------------------------
// segments (in 8-elem units): q 131072, kv 262144, Wq/Wk/Wv/Wo 32768 each
__global__ void k0_cvt(const float* __restrict__ q, const float* __restrict__ kv,
                       const float* __restrict__ Wq, const float* __restrict__ Wk,
                       const float* __restrict__ Wv, const float* __restrict__ Wo,
                       short* __restrict__ qb, short* __restrict__ kvb,
                       short* __restrict__ Wqb, short* __restrict__ Wkb,
                       short* __restrict__ Wvb, short* __restrict__ Wob) {
  int i = blockIdx.x * blockDim.x + threadIdx.x;
  const float* src; short* dst;
  if (i < 131072)                 { src = q;  dst = qb;  }
  else if ((i -= 131072) < 262144){ src = kv; dst = kvb; }
  else if ((i -= 262144) < 32768) { src = Wq; dst = Wqb; }
  else if ((i -= 32768) < 32768)  { src = Wk; dst = Wkb; }
  else if ((i -= 32768) < 32768)  { src = Wv; dst = Wvb; }
  else { i -= 32768;                src = Wo; dst = Wob; }
  const float4* s4 = reinterpret_cast<const float4*>(src) + (size_t)i * 2;
  float4 a = s4[0], b = s4[1];
  short8 o;
  o[0] = f2bf(a.x); o[1] = f2bf(a.y); o[2] = f2bf(a.z); o[3] = f2bf(a.w);
  o[4] = f2bf(b.x); o[5] = f2bf(b.y); o[6] = f2bf(b.z); o[7] = f2bf(b.w);
  *reinterpret_cast<short8*>(dst + (size_t)i * 8) = o;
}

// ---------------- K1: projections (X @ W^T) as bf16 MFMA ---------------------
// wave computes a 16(M) x 64(N) output tile, K=512 in 16 ksteps.
// wid < 1024: Q (M=2048); < 3072: K (M=4096); else V (M=4096, stored transposed)
__global__ void k1_proj(const short* __restrict__ qb, const short* __restrict__ kvb,
                        const short* __restrict__ Wqb, const short* __restrict__ Wkb,
                        const short* __restrict__ Wvb,
                        short* __restrict__ Qb, short* __restrict__ Kb,
                        short* __restrict__ VT) {
  int lane = threadIdx.x & 63, warp = threadIdx.x >> 6;
  int wid = blockIdx.x * 4 + warp;
  int lr = lane & 15, lg = lane >> 4;
  const short *src, *W; short* dst; int mt, ct, mode;
  if (wid < 1024)      { src = qb;  W = Wqb; dst = Qb; mt = wid & 127; ct = wid >> 7; mode = 0; }
  else if (wid < 3072) { int id = wid - 1024; src = kvb; W = Wkb; dst = Kb; mt = id & 255; ct = id >> 8; mode = 0; }
  else                 { int id = wid - 3072; src = kvb; W = Wvb; dst = VT; mt = id & 255; ct = id >> 8; mode = 1; }
  int m0 = mt * 16, c0 = ct * 64;
  float4v acc[4] = {};
  const short* arow = src + (m0 + lr) * 512 + 8 * lg;
#pragma unroll
  for (int kk = 0; kk < 16; ++kk) {
    short8 a = *reinterpret_cast<const short8*>(arow + kk * 32);
#pragma unroll
    for (int cs = 0; cs < 4; ++cs) {
      const short* bp = W + (c0 + cs * 16 + lr) * 512 + kk * 32 + 8 * lg;
      short8 b = *reinterpret_cast<const short8*>(bp);
      acc[cs] = __builtin_amdgcn_mfma_f32_16x16x32_bf16(a, b, acc[cs], 0, 0, 0);
    }
  }
  if (mode == 0) {
#pragma unroll
    for (int cs = 0; cs < 4; ++cs)
#pragma unroll
      for (int j = 0; j < 4; ++j)
        dst[(m0 + 4 * lg + j) * 512 + c0 + cs * 16 + lr] = f2bf(acc[cs][j]);
  } else {
    // VT flat [512][4096]: index = col*4096 + row
#pragma unroll
    for (int cs = 0; cs < 4; ++cs)
#pragma unroll
      for (int j = 0; j < 4; ++j)
        dst[(c0 + cs * 16 + lr) * 4096 + m0 + 4 * lg + j] = f2bf(acc[cs][j]);
  }
}

// ---------------- K2: pass A — per-(head,row) sum of exp(logit) --------------
// block: 4 waves, each wave = 16 rows, all 8 heads, one 512-wide r chunk
__global__ void k2_passA(const short* __restrict__ Qb, const short* __restrict__ Kb,
                         const float* __restrict__ bias, float* __restrict__ S_part) {
  int lane = threadIdx.x & 63, warp = threadIdx.x >> 6;
  int lr = lane & 15, lg = lane >> 4;
  int l0 = blockIdx.x * 64 + warp * 16;
  int chunk = blockIdx.y;
  int r_base = chunk * CHUNK;
  float sums[8][4] = {};
  const short* qrow = Qb + (l0 + lr) * 512 + 8 * lg;
#pragma unroll 1
  for (int it = 0; it < CHUNK / 32; ++it) {
    int r0 = r_base + it * 32;
    float bv[2][4];
#pragma unroll
    for (int s = 0; s < 2; ++s)
#pragma unroll
      for (int j = 0; j < 4; ++j)
        bv[s][j] = bias[(l0 + 4 * lg + j) * NR + r0 + s * 16 + lr];
#pragma unroll
    for (int h = 0; h < 8; ++h) {
      short8 a0 = *reinterpret_cast<const short8*>(qrow + h * 64);
      short8 a1 = *reinterpret_cast<const short8*>(qrow + h * 64 + 32);
#pragma unroll
      for (int s = 0; s < 2; ++s) {
        const short* kp = Kb + (r0 + s * 16 + lr) * 512 + h * 64 + 8 * lg;
        short8 b0 = *reinterpret_cast<const short8*>(kp);
        short8 b1 = *reinterpret_cast<const short8*>(kp + 32);
        float4v c = {};
        c = __builtin_amdgcn_mfma_f32_16x16x32_bf16(a0, b0, c, 0, 0, 0);
        c = __builtin_amdgcn_mfma_f32_16x16x32_bf16(a1, b1, c, 0, 0, 0);
#pragma unroll
        for (int j = 0; j < 4; ++j)
          sums[h][j] += __expf(SCALE * c[j] + bv[s][j]);
      }
    }
  }
#pragma unroll
  for (int h = 0; h < 8; ++h)
#pragma unroll
    for (int j = 0; j < 4; ++j) {
      float v = sums[h][j];
      v += __shfl_xor(v, 1, 64); v += __shfl_xor(v, 2, 64);
      v += __shfl_xor(v, 4, 64); v += __shfl_xor(v, 8, 64);
      sums[h][j] = v;
    }
  if (lr == 0) {
#pragma unroll
    for (int h = 0; h < 8; ++h)
#pragma unroll
      for (int j = 0; j < 4; ++j)
        S_part[(chunk * 8 + h) * NL + l0 + 4 * lg + j] = sums[h][j];
  }
}

// ---------------- K2b: reduce S partials -> 1/S ------------------------------
__global__ void k2b_reduceS(const float* __restrict__ S_part, float* __restrict__ Sinv) {
  int i = blockIdx.x * blockDim.x + threadIdx.x;  // h*2048 + l
  int h = i >> 11, l = i & 2047;
  float s = 0.f;
#pragma unroll
  for (int c = 0; c < NCHUNK; ++c) s += S_part[(c * 8 + h) * NL + l];
  Sinv[i] = 1.0f / s;
}

// ---------------- K3: pass B — attn_mean + PV partials -----------------------
__global__ void __launch_bounds__(256, 1)
k3_passB(const short* __restrict__ Qb, const short* __restrict__ Kb,
         const short* __restrict__ VT, const float* __restrict__ bias,
         const float* __restrict__ Sinv,
         float* __restrict__ attn_mean, short* __restrict__ ctx_part) {
  __shared__ short att[4][16][32];  // per-wave 16x32 attn tile (bf16)
  int lane = threadIdx.x & 63, warp = threadIdx.x >> 6;
  int lr = lane & 15, lg = lane >> 4;
  int l0 = blockIdx.x * 64 + warp * 16;
  int chunk = blockIdx.y;
  int r_base = chunk * CHUNK;
  float4v acc[32] = {};  // ctx acc: [h][dsub], 16 rows x 512 cols per wave
  float sinv[8][4];
#pragma unroll
  for (int h = 0; h < 8; ++h)
#pragma unroll
    for (int j = 0; j < 4; ++j)
      sinv[h][j] = Sinv[h * NL + l0 + 4 * lg + j];
  const short* qrow = Qb + (l0 + lr) * 512 + 8 * lg;
  short* myatt = &att[warp][0][0];
#pragma unroll 1
  for (int it = 0; it < CHUNK / 32; ++it) {
    int r0 = r_base + it * 32;
    float bv[2][4];
#pragma unroll
    for (int s = 0; s < 2; ++s)
#pragma unroll
      for (int j = 0; j < 4; ++j)
        bv[s][j] = bias[(l0 + 4 * lg + j) * NR + r0 + s * 16 + lr];
    float macc[2][4] = {};
#pragma unroll
    for (int h = 0; h < 8; ++h) {
      short8 a0 = *reinterpret_cast<const short8*>(qrow + h * 64);
      short8 a1 = *reinterpret_cast<const short8*>(qrow + h * 64 + 32);
#pragma unroll
      for (int s = 0; s < 2; ++s) {
        const short* kp = Kb + (r0 + s * 16 + lr) * 512 + h * 64 + 8 * lg;
        short8 b0 = *reinterpret_cast<const short8*>(kp);
        short8 b1 = *reinterpret_cast<const short8*>(kp + 32);
        float4v cc = {};
        cc = __builtin_amdgcn_mfma_f32_16x16x32_bf16(a0, b0, cc, 0, 0, 0);
        cc = __builtin_amdgcn_mfma_f32_16x16x32_bf16(a1, b1, cc, 0, 0, 0);
#pragma unroll
        for (int j = 0; j < 4; ++j) {
          float e = __expf(SCALE * cc[j] + bv[s][j]) * sinv[h][j];
          macc[s][j] += e;
          myatt[(4 * lg + j) * 32 + s * 16 + lr] = f2bf(e);  // C-layout -> LDS
        }
      }
      // re-read as A-fragment (row=lr, k=8*lg..): per-wave private, in-order LDS
      short8 pa = *reinterpret_cast<const short8*>(&att[warp][lr][8 * lg]);
#pragma unroll
      for (int ds = 0; ds < 4; ++ds) {
        const short* vp = VT + (h * 64 + ds * 16 + lr) * 4096 + r0 + 8 * lg;
        short8 vb = *reinterpret_cast<const short8*>(vp);
        acc[h * 4 + ds] = __builtin_amdgcn_mfma_f32_16x16x32_bf16(pa, vb, acc[h * 4 + ds], 0, 0, 0);
      }
    }
#pragma unroll
    for (int s = 0; s < 2; ++s)
#pragma unroll
      for (int j = 0; j < 4; ++j)
        attn_mean[(l0 + 4 * lg + j) * NR + r0 + s * 16 + lr] = macc[s][j] * 0.125f;
  }
#pragma unroll
  for (int h = 0; h < 8; ++h)
#pragma unroll
    for (int ds = 0; ds < 4; ++ds)
#pragma unroll
      for (int j = 0; j < 4; ++j)
        ctx_part[(chunk * NL + l0 + 4 * lg + j) * 512 + h * 64 + ds * 16 + lr] =
            f2bf(acc[h * 4 + ds][j]);
}

// ---------------- K4: ctx @ Wo^T + bo + q, LayerNorm -------------------------
__global__ void k4_out(const short* __restrict__ ctx_part, const short* __restrict__ Wob,
                       const float* __restrict__ q, const float* __restrict__ bo,
                       const float* __restrict__ gamma, const float* __restrict__ beta,
                       float* __restrict__ out) {
  __shared__ float xs[16][512];
  int lane = threadIdx.x & 63, warp = threadIdx.x >> 6;
  int lr = lane & 15, lg = lane >> 4;
  int l0 = blockIdx.x * 16;
  short8 afr[16];
#pragma unroll
  for (int kk = 0; kk < 16; ++kk) {
    float sm[8] = {};
#pragma unroll
    for (int c = 0; c < NCHUNK; ++c) {
      const short* p = ctx_part + ((size_t)(c * NL + l0 + lr)) * 512 + kk * 32 + 8 * lg;
      short8 v = *reinterpret_cast<const short8*>(p);
#pragma unroll
      for (int u = 0; u < 8; ++u) sm[u] += bf2f(v[u]);
    }
    short8 a;
#pragma unroll
    for (int u = 0; u < 8; ++u) a[u] = f2bf(sm[u]);
    afr[kk] = a;
  }
#pragma unroll 1
  for (int cs = 0; cs < 8; ++cs) {
    int col0 = warp * 128 + cs * 16;
    float4v c = {};
#pragma unroll
    for (int kk = 0; kk < 16; ++kk) {
      const short* bp = Wob + (col0 + lr) * 512 + kk * 32 + 8 * lg;
      short8 b = *reinterpret_cast<const short8*>(bp);
      c = __builtin_amdgcn_mfma_f32_16x16x32_bf16(afr[kk], b, c, 0, 0, 0);
    }
#pragma unroll
    for (int j = 0; j < 4; ++j) {
      int row = l0 + 4 * lg + j, col = col0 + lr;
      xs[4 * lg + j][col] = c[j] + bo[col] + q[row * 512 + col];
    }
  }
  __syncthreads();
  int tid = threadIdx.x;
  int rl = tid >> 4, g = tid & 15;
  float sum = 0.f;
#pragma unroll
  for (int i = 0; i < 32; ++i) sum += xs[rl][g + 16 * i];
  sum += __shfl_xor(sum, 1, 64); sum += __shfl_xor(sum, 2, 64);
  sum += __shfl_xor(sum, 4, 64); sum += __shfl_xor(sum, 8, 64);
  float mu = sum * (1.0f / 512.0f);
  float vs = 0.f;
#pragma unroll
  for (int i = 0; i < 32; ++i) { float d = xs[rl][g + 16 * i] - mu; vs += d * d; }
  vs += __shfl_xor(vs, 1, 64); vs += __shfl_xor(vs, 2, 64);
  vs += __shfl_xor(vs, 4, 64); vs += __shfl_xor(vs, 8, 64);
  float rs = rsqrtf(vs * (1.0f / 512.0f) + LN_EPS);
#pragma unroll
  for (int i = 0; i < 32; ++i) {
    int cc = g + 16 * i;
    out[(l0 + rl) * 512 + cc] = (xs[rl][cc] - mu) * rs * gamma[cc] + beta[cc];
  }
}

extern "C" void kernel_launch(void* const* d_in, const int* in_sizes, int n_in,
                              void* d_out, int out_size, void* d_ws, size_t ws_size,
                              hipStream_t stream) {
  const float* q     = (const float*)d_in[0];
  const float* kv    = (const float*)d_in[1];
  const float* bias  = (const float*)d_in[2];
  const float* Wq    = (const float*)d_in[3];
  const float* Wk    = (const float*)d_in[4];
  const float* Wv    = (const float*)d_in[5];
  const float* Wo    = (const float*)d_in[6];
  const float* bo    = (const float*)d_in[7];
  const float* gamma = (const float*)d_in[8];
  const float* beta  = (const float*)d_in[9];
  float* out = (float*)d_out;
  float* attn_mean = out + (size_t)NL * 512;

  char* ws = (char*)d_ws;
  short* qb       = (short*)(ws + 0);         // 2 MB
  short* kvb      = (short*)(ws + 2097152);   // 4 MB
  short* Wqb      = (short*)(ws + 6291456);   // 512 KB
  short* Wkb      = (short*)(ws + 6815744);
  short* Wvb      = (short*)(ws + 7340032);
  short* Wob      = (short*)(ws + 7864320);
  short* Qb       = (short*)(ws + 8388608);   // 2 MB
  short* Kb       = (short*)(ws + 10485760);  // 4 MB
  short* VT       = (short*)(ws + 14680064);  // 4 MB
  float* S_part   = (float*)(ws + 18874368);  // 512 KB
  float* Sinv     = (float*)(ws + 19398656);  // 64 KB
  short* ctx_part = (short*)(ws + 19464192);  // 16 MB  (total ~36.2 MB)

  k0_cvt<<<2048, 256, 0, stream>>>(q, kv, Wq, Wk, Wv, Wo, qb, kvb, Wqb, Wkb, Wvb, Wob);
  k1_proj<<<1280, 256, 0, stream>>>(qb, kvb, Wqb, Wkb, Wvb, Qb, Kb, VT);
  k2_passA<<<dim3(32, 8), 256, 0, stream>>>(Qb, Kb, bias, S_part);
  k2b_reduceS<<<64, 256, 0, stream>>>(S_part, Sinv);
  k3_passB<<<dim3(32, 8), 256, 0, stream>>>(Qb, Kb, VT, bias, Sinv, attn_mean, ctx_part);
  k4_out<<<128, 256, 0, stream>>>(ctx_part, Wob, q, bo, gamma, beta, out);
}

// Round 3
// 379.049 us; speedup vs baseline: 1.4194x; 1.4194x over previous
//
#include <hip/hip_runtime.h>
#include <hip/hip_bf16.h>
#include <stdint.h>

#define NL 2048
#define NR 4096
#define NCHUNK 8
#define CHUNK (NR / NCHUNK) /* 512 */
#define SCALE 0.125f
#define LN_EPS 1e-5f

typedef __attribute__((ext_vector_type(8))) short short8;  // 8 bf16 in 4 VGPRs
typedef __attribute__((ext_vector_type(4))) float float4v;

static __device__ __forceinline__ short f2bf(float f) {
  union { float f; uint32_t u; } v; v.f = f;
  uint32_t u = v.u;
  uint32_t r = (u + 0x7FFFu + ((u >> 16) & 1u)) >> 16;  // RNE
  return (short)(r & 0xFFFFu);
}
static __device__ __forceinline__ float bf2f(short b) {
  union { uint32_t u; float f; } v; v.u = ((uint32_t)(uint16_t)b) << 16;
  return v.f;
}

// ---------------- K0: fp32 -> bf16 conversions -------------------------------
__global__ void k0_cvt(const float* __restrict__ q, const float* __restrict__ kv,
                       const float* __restrict__ Wq, const float* __restrict__ Wk,
                       const float* __restrict__ Wv, const float* __restrict__ Wo,
                       short* __restrict__ qb, short* __restrict__ kvb,
                       short* __restrict__ Wqb, short* __restrict__ Wkb,
                       short* __restrict__ Wvb, short* __restrict__ Wob) {
  int i = blockIdx.x * blockDim.x + threadIdx.x;
  const float* src; short* dst;
  if (i < 131072)                 { src = q;  dst = qb;  }
  else if ((i -= 131072) < 262144){ src = kv; dst = kvb; }
  else if ((i -= 262144) < 32768) { src = Wq; dst = Wqb; }
  else if ((i -= 32768) < 32768)  { src = Wk; dst = Wkb; }
  else if ((i -= 32768) < 32768)  { src = Wv; dst = Wvb; }
  else { i -= 32768;                src = Wo; dst = Wob; }
  const float4* s4 = reinterpret_cast<const float4*>(src) + (size_t)i * 2;
  float4 a = s4[0], b = s4[1];
  short8 o;
  o[0] = f2bf(a.x); o[1] = f2bf(a.y); o[2] = f2bf(a.z); o[3] = f2bf(a.w);
  o[4] = f2bf(b.x); o[5] = f2bf(b.y); o[6] = f2bf(b.z); o[7] = f2bf(b.w);
  *reinterpret_cast<short8*>(dst + (size_t)i * 8) = o;
}

// ---------------- K1: projections (X @ W^T) as bf16 MFMA ---------------------
__global__ void k1_proj(const short* __restrict__ qb, const short* __restrict__ kvb,
                        const short* __restrict__ Wqb, const short* __restrict__ Wkb,
                        const short* __restrict__ Wvb,
                        short* __restrict__ Qb, short* __restrict__ Kb,
                        short* __restrict__ VT) {
  int lane = threadIdx.x & 63, warp = threadIdx.x >> 6;
  int wid = blockIdx.x * 4 + warp;
  int lr = lane & 15, lg = lane >> 4;
  const short *src, *W; short* dst; int mt, ct, mode;
  if (wid < 1024)      { src = qb;  W = Wqb; dst = Qb; mt = wid & 127; ct = wid >> 7; mode = 0; }
  else if (wid < 3072) { int id = wid - 1024; src = kvb; W = Wkb; dst = Kb; mt = id & 255; ct = id >> 8; mode = 0; }
  else                 { int id = wid - 3072; src = kvb; W = Wvb; dst = VT; mt = id & 255; ct = id >> 8; mode = 1; }
  int m0 = mt * 16, c0 = ct * 64;
  float4v acc[4] = {};
  const short* arow = src + (m0 + lr) * 512 + 8 * lg;
#pragma unroll
  for (int kk = 0; kk < 16; ++kk) {
    short8 a = *reinterpret_cast<const short8*>(arow + kk * 32);
#pragma unroll
    for (int cs = 0; cs < 4; ++cs) {
      const short* bp = W + (c0 + cs * 16 + lr) * 512 + kk * 32 + 8 * lg;
      short8 b = *reinterpret_cast<const short8*>(bp);
      acc[cs] = __builtin_amdgcn_mfma_f32_16x16x32_bf16(a, b, acc[cs], 0, 0, 0);
    }
  }
  if (mode == 0) {
#pragma unroll
    for (int cs = 0; cs < 4; ++cs)
#pragma unroll
      for (int j = 0; j < 4; ++j)
        dst[(m0 + 4 * lg + j) * 512 + c0 + cs * 16 + lr] = f2bf(acc[cs][j]);
  } else {
#pragma unroll
    for (int cs = 0; cs < 4; ++cs)
#pragma unroll
      for (int j = 0; j < 4; ++j)
        dst[(c0 + cs * 16 + lr) * 4096 + m0 + 4 * lg + j] = f2bf(acc[cs][j]);
  }
}

// ---------------- K2: pass A — per-(head,row) sum of exp(logit) --------------
// block: 4 waves over SAME 16 rows; wave w handles heads {2w, 2w+1}
__global__ void __launch_bounds__(256, 4)
k2_passA(const short* __restrict__ Qb, const short* __restrict__ Kb,
         const float* __restrict__ bias, float* __restrict__ S_part) {
  int lane = threadIdx.x & 63, w = threadIdx.x >> 6;
  int lr = lane & 15, lg = lane >> 4;
  int l0 = blockIdx.x * 16;
  int chunk = blockIdx.y;
  int r_base = chunk * CHUNK;
  float sums[2][4] = {};
  const short* qrow = Qb + (l0 + lr) * 512 + 8 * lg;
  short8 qa[2][2];
#pragma unroll
  for (int hh = 0; hh < 2; ++hh) {
    qa[hh][0] = *reinterpret_cast<const short8*>(qrow + (2 * w + hh) * 64);
    qa[hh][1] = *reinterpret_cast<const short8*>(qrow + (2 * w + hh) * 64 + 32);
  }
#pragma unroll 1
  for (int it = 0; it < CHUNK / 32; ++it) {
    int r0 = r_base + it * 32;
    float bv[2][4];
#pragma unroll
    for (int s = 0; s < 2; ++s)
#pragma unroll
      for (int j = 0; j < 4; ++j)
        bv[s][j] = bias[(l0 + 4 * lg + j) * NR + r0 + s * 16 + lr];
#pragma unroll
    for (int hh = 0; hh < 2; ++hh) {
      int h = 2 * w + hh;
#pragma unroll
      for (int s = 0; s < 2; ++s) {
        const short* kp = Kb + (r0 + s * 16 + lr) * 512 + h * 64 + 8 * lg;
        short8 b0 = *reinterpret_cast<const short8*>(kp);
        short8 b1 = *reinterpret_cast<const short8*>(kp + 32);
        float4v c = {};
        c = __builtin_amdgcn_mfma_f32_16x16x32_bf16(qa[hh][0], b0, c, 0, 0, 0);
        c = __builtin_amdgcn_mfma_f32_16x16x32_bf16(qa[hh][1], b1, c, 0, 0, 0);
#pragma unroll
        for (int j = 0; j < 4; ++j)
          sums[hh][j] += __expf(SCALE * c[j] + bv[s][j]);
      }
    }
  }
#pragma unroll
  for (int hh = 0; hh < 2; ++hh)
#pragma unroll
    for (int j = 0; j < 4; ++j) {
      float v = sums[hh][j];
      v += __shfl_xor(v, 1, 64); v += __shfl_xor(v, 2, 64);
      v += __shfl_xor(v, 4, 64); v += __shfl_xor(v, 8, 64);
      sums[hh][j] = v;
    }
  if (lr == 0) {
#pragma unroll
    for (int hh = 0; hh < 2; ++hh)
#pragma unroll
      for (int j = 0; j < 4; ++j)
        S_part[(chunk * 8 + 2 * w + hh) * NL + l0 + 4 * lg + j] = sums[hh][j];
  }
}

// ---------------- K2b: reduce S partials -> 1/S ------------------------------
__global__ void k2b_reduceS(const float* __restrict__ S_part, float* __restrict__ Sinv) {
  int i = blockIdx.x * blockDim.x + threadIdx.x;  // h*2048 + l
  int h = i >> 11, l = i & 2047;
  float s = 0.f;
#pragma unroll
  for (int c = 0; c < NCHUNK; ++c) s += S_part[(c * 8 + h) * NL + l];
  Sinv[i] = 1.0f / s;
}

// ---------------- K3: pass B — attn_mean + PV partials -----------------------
// block: 4 waves over SAME 16 rows; wave w handles heads {2w, 2w+1};
// attn_mean reduced across waves via LDS each r-step
__global__ void __launch_bounds__(256, 4)
k3_passB(const short* __restrict__ Qb, const short* __restrict__ Kb,
         const short* __restrict__ VT, const float* __restrict__ bias,
         const float* __restrict__ Sinv,
         float* __restrict__ attn_mean, short* __restrict__ ctx_part) {
  __shared__ short att[4][16][32];     // per-wave 16x32 attn tile (bf16)
  __shared__ float maccLDS[4][16][32]; // per-wave attn_mean partial
  int lane = threadIdx.x & 63, w = threadIdx.x >> 6;
  int lr = lane & 15, lg = lane >> 4;
  int l0 = blockIdx.x * 16;
  int chunk = blockIdx.y;
  int r_base = chunk * CHUNK;
  float4v acc[8] = {};  // [hh][ds]: 16 rows x 128 cols per wave
  float sinv[2][4];
#pragma unroll
  for (int hh = 0; hh < 2; ++hh)
#pragma unroll
    for (int j = 0; j < 4; ++j)
      sinv[hh][j] = Sinv[(2 * w + hh) * NL + l0 + 4 * lg + j];
  const short* qrow = Qb + (l0 + lr) * 512 + 8 * lg;
  short8 qa[2][2];
#pragma unroll
  for (int hh = 0; hh < 2; ++hh) {
    qa[hh][0] = *reinterpret_cast<const short8*>(qrow + (2 * w + hh) * 64);
    qa[hh][1] = *reinterpret_cast<const short8*>(qrow + (2 * w + hh) * 64 + 32);
  }
  short* myatt = &att[w][0][0];
#pragma unroll 1
  for (int it = 0; it < CHUNK / 32; ++it) {
    int r0 = r_base + it * 32;
    float bv[2][4];
#pragma unroll
    for (int s = 0; s < 2; ++s)
#pragma unroll
      for (int j = 0; j < 4; ++j)
        bv[s][j] = bias[(l0 + 4 * lg + j) * NR + r0 + s * 16 + lr];
    float macc[2][4] = {};
#pragma unroll
    for (int hh = 0; hh < 2; ++hh) {
      int h = 2 * w + hh;
#pragma unroll
      for (int s = 0; s < 2; ++s) {
        const short* kp = Kb + (r0 + s * 16 + lr) * 512 + h * 64 + 8 * lg;
        short8 b0 = *reinterpret_cast<const short8*>(kp);
        short8 b1 = *reinterpret_cast<const short8*>(kp + 32);
        float4v cc = {};
        cc = __builtin_amdgcn_mfma_f32_16x16x32_bf16(qa[hh][0], b0, cc, 0, 0, 0);
        cc = __builtin_amdgcn_mfma_f32_16x16x32_bf16(qa[hh][1], b1, cc, 0, 0, 0);
#pragma unroll
        for (int j = 0; j < 4; ++j) {
          float e = __expf(SCALE * cc[j] + bv[s][j]) * sinv[hh][j];
          macc[s][j] += e;
          myatt[(4 * lg + j) * 32 + s * 16 + lr] = f2bf(e);  // C-layout -> LDS
        }
      }
      // re-read as A-fragment (row=lr, k=8*lg..): per-wave private, in-order LDS
      short8 pa = *reinterpret_cast<const short8*>(&att[w][lr][8 * lg]);
#pragma unroll
      for (int ds = 0; ds < 4; ++ds) {
        const short* vp = VT + (h * 64 + ds * 16 + lr) * 4096 + r0 + 8 * lg;
        short8 vb = *reinterpret_cast<const short8*>(vp);
        acc[hh * 4 + ds] = __builtin_amdgcn_mfma_f32_16x16x32_bf16(pa, vb, acc[hh * 4 + ds], 0, 0, 0);
      }
    }
    // cross-wave attn_mean reduction (macc covers this wave's 2 heads)
#pragma unroll
    for (int s = 0; s < 2; ++s)
#pragma unroll
      for (int j = 0; j < 4; ++j)
        maccLDS[w][4 * lg + j][s * 16 + lr] = macc[s][j];
    __syncthreads();
    {
      int t = threadIdx.x;
      int row = t >> 4, col = (t & 15) * 2;
      float2 v;
      v.x = (maccLDS[0][row][col] + maccLDS[1][row][col] +
             maccLDS[2][row][col] + maccLDS[3][row][col]) * 0.125f;
      v.y = (maccLDS[0][row][col + 1] + maccLDS[1][row][col + 1] +
             maccLDS[2][row][col + 1] + maccLDS[3][row][col + 1]) * 0.125f;
      *reinterpret_cast<float2*>(&attn_mean[(size_t)(l0 + row) * NR + r0 + col]) = v;
    }
    __syncthreads();
  }
#pragma unroll
  for (int hh = 0; hh < 2; ++hh)
#pragma unroll
    for (int ds = 0; ds < 4; ++ds)
#pragma unroll
      for (int j = 0; j < 4; ++j)
        ctx_part[(chunk * NL + l0 + 4 * lg + j) * 512 + (2 * w + hh) * 64 + ds * 16 + lr] =
            f2bf(acc[hh * 4 + ds][j]);
}

// ---------------- K4pre: sum ctx_part chunks ---------------------------------
__global__ void k4pre(const short* __restrict__ ctx_part, short* __restrict__ ctxsum) {
  int i = blockIdx.x * blockDim.x + threadIdx.x;  // 131072 threads, 8 bf16 each
  float sm[8] = {};
#pragma unroll
  for (int c = 0; c < NCHUNK; ++c) {
    short8 v = *reinterpret_cast<const short8*>(ctx_part + (size_t)c * NL * 512 + (size_t)i * 8);
#pragma unroll
    for (int u = 0; u < 8; ++u) sm[u] += bf2f(v[u]);
  }
  short8 o;
#pragma unroll
  for (int u = 0; u < 8; ++u) o[u] = f2bf(sm[u]);
  *reinterpret_cast<short8*>(ctxsum + (size_t)i * 8) = o;
}

// ---------------- K4: ctx @ Wo^T + bo + q, LayerNorm -------------------------
__global__ void k4_out(const short* __restrict__ ctxsum, const short* __restrict__ Wob,
                       const float* __restrict__ q, const float* __restrict__ bo,
                       const float* __restrict__ gamma, const float* __restrict__ beta,
                       float* __restrict__ out) {
  __shared__ float xs[16][512];
  int lane = threadIdx.x & 63, warp = threadIdx.x >> 6;
  int lr = lane & 15, lg = lane >> 4;
  int l0 = blockIdx.x * 16;
  short8 afr[16];
#pragma unroll
  for (int kk = 0; kk < 16; ++kk)
    afr[kk] = *reinterpret_cast<const short8*>(ctxsum + (l0 + lr) * 512 + kk * 32 + 8 * lg);
#pragma unroll 1
  for (int cs = 0; cs < 8; ++cs) {
    int col0 = warp * 128 + cs * 16;
    float4v c = {};
#pragma unroll
    for (int kk = 0; kk < 16; ++kk) {
      const short* bp = Wob + (col0 + lr) * 512 + kk * 32 + 8 * lg;
      short8 b = *reinterpret_cast<const short8*>(bp);
      c = __builtin_amdgcn_mfma_f32_16x16x32_bf16(afr[kk], b, c, 0, 0, 0);
    }
#pragma unroll
    for (int j = 0; j < 4; ++j) {
      int row = l0 + 4 * lg + j, col = col0 + lr;
      xs[4 * lg + j][col] = c[j] + bo[col] + q[row * 512 + col];
    }
  }
  __syncthreads();
  int tid = threadIdx.x;
  int rl = tid >> 4, g = tid & 15;
  float sum = 0.f;
#pragma unroll
  for (int i = 0; i < 32; ++i) sum += xs[rl][g + 16 * i];
  sum += __shfl_xor(sum, 1, 64); sum += __shfl_xor(sum, 2, 64);
  sum += __shfl_xor(sum, 4, 64); sum += __shfl_xor(sum, 8, 64);
  float mu = sum * (1.0f / 512.0f);
  float vs = 0.f;
#pragma unroll
  for (int i = 0; i < 32; ++i) { float d = xs[rl][g + 16 * i] - mu; vs += d * d; }
  vs += __shfl_xor(vs, 1, 64); vs += __shfl_xor(vs, 2, 64);
  vs += __shfl_xor(vs, 4, 64); vs += __shfl_xor(vs, 8, 64);
  float rs = rsqrtf(vs * (1.0f / 512.0f) + LN_EPS);
#pragma unroll
  for (int i = 0; i < 32; ++i) {
    int cc = g + 16 * i;
    out[(l0 + rl) * 512 + cc] = (xs[rl][cc] - mu) * rs * gamma[cc] + beta[cc];
  }
}

extern "C" void kernel_launch(void* const* d_in, const int* in_sizes, int n_in,
                              void* d_out, int out_size, void* d_ws, size_t ws_size,
                              hipStream_t stream) {
  const float* q     = (const float*)d_in[0];
  const float* kv    = (const float*)d_in[1];
  const float* bias  = (const float*)d_in[2];
  const float* Wq    = (const float*)d_in[3];
  const float* Wk    = (const float*)d_in[4];
  const float* Wv    = (const float*)d_in[5];
  const float* Wo    = (const float*)d_in[6];
  const float* bo    = (const float*)d_in[7];
  const float* gamma = (const float*)d_in[8];
  const float* beta  = (const float*)d_in[9];
  float* out = (float*)d_out;
  float* attn_mean = out + (size_t)NL * 512;

  char* ws = (char*)d_ws;
  short* qb       = (short*)(ws + 0);         // 2 MB
  short* kvb      = (short*)(ws + 2097152);   // 4 MB
  short* Wqb      = (short*)(ws + 6291456);   // 512 KB
  short* Wkb      = (short*)(ws + 6815744);
  short* Wvb      = (short*)(ws + 7340032);
  short* Wob      = (short*)(ws + 7864320);
  short* Qb       = (short*)(ws + 8388608);   // 2 MB
  short* Kb       = (short*)(ws + 10485760);  // 4 MB
  short* VT       = (short*)(ws + 14680064);  // 4 MB
  float* S_part   = (float*)(ws + 18874368);  // 512 KB
  float* Sinv     = (float*)(ws + 19398656);  // 64 KB
  short* ctx_part = (short*)(ws + 19464192);  // 16 MB
  short* ctxsum   = (short*)(ws + 36241408);  // 2 MB  (total ~38.2 MB)

  k0_cvt<<<2048, 256, 0, stream>>>(q, kv, Wq, Wk, Wv, Wo, qb, kvb, Wqb, Wkb, Wvb, Wob);
  k1_proj<<<1280, 256, 0, stream>>>(qb, kvb, Wqb, Wkb, Wvb, Qb, Kb, VT);
  k2_passA<<<dim3(128, 8), 256, 0, stream>>>(Qb, Kb, bias, S_part);
  k2b_reduceS<<<64, 256, 0, stream>>>(S_part, Sinv);
  k3_passB<<<dim3(128, 8), 256, 0, stream>>>(Qb, Kb, VT, bias, Sinv, attn_mean, ctx_part);
  k4pre<<<512, 256, 0, stream>>>(ctx_part, ctxsum);
  k4_out<<<128, 256, 0, stream>>>(ctxsum, Wob, q, bo, gamma, beta, out);
}

// Round 4
// 374.002 us; speedup vs baseline: 1.4385x; 1.0135x over previous
//
#include <hip/hip_runtime.h>
#include <hip/hip_bf16.h>
#include <stdint.h>

#define NL 2048
#define NR 4096
#define NCHUNK 8
#define CHUNK (NR / NCHUNK) /* 512 */
#define SCALE 0.125f
#define LN_EPS 1e-5f

typedef __attribute__((ext_vector_type(8))) short short8;  // 8 bf16 in 4 VGPRs
typedef __attribute__((ext_vector_type(4))) float float4v;

static __device__ __forceinline__ short f2bf(float f) {
  union { float f; uint32_t u; } v; v.f = f;
  uint32_t u = v.u;
  uint32_t r = (u + 0x7FFFu + ((u >> 16) & 1u)) >> 16;  // RNE
  return (short)(r & 0xFFFFu);
}
static __device__ __forceinline__ float bf2f(short b) {
  union { uint32_t u; float f; } v; v.u = ((uint32_t)(uint16_t)b) << 16;
  return v.f;
}

// ---------------- K0: fp32 -> bf16 conversions -------------------------------
__global__ void k0_cvt(const float* __restrict__ q, const float* __restrict__ kv,
                       const float* __restrict__ Wq, const float* __restrict__ Wk,
                       const float* __restrict__ Wv, const float* __restrict__ Wo,
                       short* __restrict__ qb, short* __restrict__ kvb,
                       short* __restrict__ Wqb, short* __restrict__ Wkb,
                       short* __restrict__ Wvb, short* __restrict__ Wob) {
  int i = blockIdx.x * blockDim.x + threadIdx.x;
  const float* src; short* dst;
  if (i < 131072)                 { src = q;  dst = qb;  }
  else if ((i -= 131072) < 262144){ src = kv; dst = kvb; }
  else if ((i -= 262144) < 32768) { src = Wq; dst = Wqb; }
  else if ((i -= 32768) < 32768)  { src = Wk; dst = Wkb; }
  else if ((i -= 32768) < 32768)  { src = Wv; dst = Wvb; }
  else { i -= 32768;                src = Wo; dst = Wob; }
  const float4* s4 = reinterpret_cast<const float4*>(src) + (size_t)i * 2;
  float4 a = s4[0], b = s4[1];
  short8 o;
  o[0] = f2bf(a.x); o[1] = f2bf(a.y); o[2] = f2bf(a.z); o[3] = f2bf(a.w);
  o[4] = f2bf(b.x); o[5] = f2bf(b.y); o[6] = f2bf(b.z); o[7] = f2bf(b.w);
  *reinterpret_cast<short8*>(dst + (size_t)i * 8) = o;
}

// ---------------- K1: projections (X @ W^T) as bf16 MFMA ---------------------
__global__ void k1_proj(const short* __restrict__ qb, const short* __restrict__ kvb,
                        const short* __restrict__ Wqb, const short* __restrict__ Wkb,
                        const short* __restrict__ Wvb,
                        short* __restrict__ Qb, short* __restrict__ Kb,
                        short* __restrict__ VT) {
  int lane = threadIdx.x & 63, warp = threadIdx.x >> 6;
  int wid = blockIdx.x * 4 + warp;
  int lr = lane & 15, lg = lane >> 4;
  const short *src, *W; short* dst; int mt, ct, mode;
  if (wid < 1024)      { src = qb;  W = Wqb; dst = Qb; mt = wid & 127; ct = wid >> 7; mode = 0; }
  else if (wid < 3072) { int id = wid - 1024; src = kvb; W = Wkb; dst = Kb; mt = id & 255; ct = id >> 8; mode = 0; }
  else                 { int id = wid - 3072; src = kvb; W = Wvb; dst = VT; mt = id & 255; ct = id >> 8; mode = 1; }
  int m0 = mt * 16, c0 = ct * 64;
  float4v acc[4] = {};
  const short* arow = src + (m0 + lr) * 512 + 8 * lg;
#pragma unroll
  for (int kk = 0; kk < 16; ++kk) {
    short8 a = *reinterpret_cast<const short8*>(arow + kk * 32);
#pragma unroll
    for (int cs = 0; cs < 4; ++cs) {
      const short* bp = W + (c0 + cs * 16 + lr) * 512 + kk * 32 + 8 * lg;
      short8 b = *reinterpret_cast<const short8*>(bp);
      acc[cs] = __builtin_amdgcn_mfma_f32_16x16x32_bf16(a, b, acc[cs], 0, 0, 0);
    }
  }
  if (mode == 0) {
#pragma unroll
    for (int cs = 0; cs < 4; ++cs)
#pragma unroll
      for (int j = 0; j < 4; ++j)
        dst[(m0 + 4 * lg + j) * 512 + c0 + cs * 16 + lr] = f2bf(acc[cs][j]);
  } else {
#pragma unroll
    for (int cs = 0; cs < 4; ++cs)
#pragma unroll
      for (int j = 0; j < 4; ++j)
        dst[(c0 + cs * 16 + lr) * 4096 + m0 + 4 * lg + j] = f2bf(acc[cs][j]);
  }
}

// ---------------- K2: pass A — per-(head,row) sum of exp(logit) --------------
// block: 8 waves over SAME 16 rows; wave w = head w. No LDS, no barriers.
__global__ void __launch_bounds__(512, 8)
k2_passA(const short* __restrict__ Qb, const short* __restrict__ Kb,
         const float* __restrict__ bias, float* __restrict__ S_part) {
  int lane = threadIdx.x & 63, w = threadIdx.x >> 6;  // w = head
  int lr = lane & 15, lg = lane >> 4;
  int l0 = blockIdx.x * 16;
  int chunk = blockIdx.y;
  int r_base = chunk * CHUNK;
  float sums[4] = {};
  const short* qrow = Qb + (l0 + lr) * 512 + 8 * lg;
  short8 qa0 = *reinterpret_cast<const short8*>(qrow + w * 64);
  short8 qa1 = *reinterpret_cast<const short8*>(qrow + w * 64 + 32);
#pragma unroll 1
  for (int it = 0; it < CHUNK / 32; ++it) {
    int r0 = r_base + it * 32;
    float bv[2][4];
#pragma unroll
    for (int s = 0; s < 2; ++s)
#pragma unroll
      for (int j = 0; j < 4; ++j)
        bv[s][j] = bias[(l0 + 4 * lg + j) * NR + r0 + s * 16 + lr];
    float4v cc[2];
#pragma unroll
    for (int s = 0; s < 2; ++s) {
      const short* kp = Kb + (r0 + s * 16 + lr) * 512 + w * 64 + 8 * lg;
      short8 b0 = *reinterpret_cast<const short8*>(kp);
      short8 b1 = *reinterpret_cast<const short8*>(kp + 32);
      float4v c = {};
      c = __builtin_amdgcn_mfma_f32_16x16x32_bf16(qa0, b0, c, 0, 0, 0);
      c = __builtin_amdgcn_mfma_f32_16x16x32_bf16(qa1, b1, c, 0, 0, 0);
      cc[s] = c;
    }
#pragma unroll
    for (int s = 0; s < 2; ++s)
#pragma unroll
      for (int j = 0; j < 4; ++j)
        sums[j] += __expf(SCALE * cc[s][j] + bv[s][j]);
  }
#pragma unroll
  for (int j = 0; j < 4; ++j) {
    float v = sums[j];
    v += __shfl_xor(v, 1, 64); v += __shfl_xor(v, 2, 64);
    v += __shfl_xor(v, 4, 64); v += __shfl_xor(v, 8, 64);
    sums[j] = v;
  }
  if (lr == 0) {
#pragma unroll
    for (int j = 0; j < 4; ++j)
      S_part[(chunk * 8 + w) * NL + l0 + 4 * lg + j] = sums[j];
  }
}

// ---------------- K2b: reduce S partials -> 1/S ------------------------------
__global__ void k2b_reduceS(const float* __restrict__ S_part, float* __restrict__ Sinv) {
  int i = blockIdx.x * blockDim.x + threadIdx.x;  // h*2048 + l
  int h = i >> 11, l = i & 2047;
  float s = 0.f;
#pragma unroll
  for (int c = 0; c < NCHUNK; ++c) s += S_part[(c * 8 + h) * NL + l];
  Sinv[i] = 1.0f / s;
}

// ---------------- K3: pass B — attn_mean + PV partials -----------------------
// block: 8 waves over SAME 16 rows; wave w = head w. PV runs on RAW exp
// values; sinv folded into epilogue scale + attn_mean reduce.
__global__ void __launch_bounds__(512, 8)
k3_passB(const short* __restrict__ Qb, const short* __restrict__ Kb,
         const short* __restrict__ VT, const float* __restrict__ bias,
         const float* __restrict__ Sinv,
         float* __restrict__ attn_mean, short* __restrict__ ctx_part) {
  __shared__ __align__(16) short att[8][16][32];  // per-wave 16x32 raw-e tile (8 KB)
  __shared__ float maccLDS[8][16][32];            // per-head attn_mean partial (16 KB)
  int lane = threadIdx.x & 63, w = threadIdx.x >> 6;  // w = head
  int lr = lane & 15, lg = lane >> 4;
  int l0 = blockIdx.x * 16;
  int chunk = blockIdx.y;
  int r_base = chunk * CHUNK;
  float4v acc[4] = {};  // [ds]: 16 rows x 64 d-cols, RAW (unnormalized)
  float sinv[4];
#pragma unroll
  for (int j = 0; j < 4; ++j)
    sinv[j] = Sinv[w * NL + l0 + 4 * lg + j];
  const short* qrow = Qb + (l0 + lr) * 512 + 8 * lg;
  short8 qa0 = *reinterpret_cast<const short8*>(qrow + w * 64);
  short8 qa1 = *reinterpret_cast<const short8*>(qrow + w * 64 + 32);
  short* myatt = &att[w][0][0];
#pragma unroll 1
  for (int it = 0; it < CHUNK / 32; ++it) {
    int r0 = r_base + it * 32;
    float bv[2][4];
#pragma unroll
    for (int s = 0; s < 2; ++s)
#pragma unroll
      for (int j = 0; j < 4; ++j)
        bv[s][j] = bias[(l0 + 4 * lg + j) * NR + r0 + s * 16 + lr];
    // QK^T for both 16-col subtiles first (independent MFMA chains)
    float4v cc[2];
#pragma unroll
    for (int s = 0; s < 2; ++s) {
      const short* kp = Kb + (r0 + s * 16 + lr) * 512 + w * 64 + 8 * lg;
      short8 b0 = *reinterpret_cast<const short8*>(kp);
      short8 b1 = *reinterpret_cast<const short8*>(kp + 32);
      float4v c = {};
      c = __builtin_amdgcn_mfma_f32_16x16x32_bf16(qa0, b0, c, 0, 0, 0);
      c = __builtin_amdgcn_mfma_f32_16x16x32_bf16(qa1, b1, c, 0, 0, 0);
      cc[s] = c;
    }
    float macc[2][4];
#pragma unroll
    for (int s = 0; s < 2; ++s)
#pragma unroll
      for (int j = 0; j < 4; ++j) {
        float e = __expf(SCALE * cc[s][j] + bv[s][j]);  // RAW exp, no sinv
        macc[s][j] = e;
        myatt[(4 * lg + j) * 32 + s * 16 + lr] = f2bf(e);  // C-layout -> LDS
      }
    // re-read as A-fragment (row=lr, k=8*lg..): wave-private, in-order LDS
    short8 pa = *reinterpret_cast<const short8*>(&att[w][lr][8 * lg]);
#pragma unroll
    for (int ds = 0; ds < 4; ++ds) {
      const short* vp = VT + (w * 64 + ds * 16 + lr) * 4096 + r0 + 8 * lg;
      short8 vb = *reinterpret_cast<const short8*>(vp);
      acc[ds] = __builtin_amdgcn_mfma_f32_16x16x32_bf16(pa, vb, acc[ds], 0, 0, 0);
    }
    // cross-head attn_mean reduction (sinv folded in here)
#pragma unroll
    for (int s = 0; s < 2; ++s)
#pragma unroll
      for (int j = 0; j < 4; ++j)
        maccLDS[w][4 * lg + j][s * 16 + lr] = macc[s][j] * sinv[j];
    __syncthreads();
    {
      int t = threadIdx.x;
      int row = t >> 5, col = t & 31;
      float v = 0.f;
#pragma unroll
      for (int hh = 0; hh < 8; ++hh) v += maccLDS[hh][row][col];
      attn_mean[(size_t)(l0 + row) * NR + r0 + col] = v * 0.125f;
    }
    __syncthreads();
  }
#pragma unroll
  for (int ds = 0; ds < 4; ++ds)
#pragma unroll
    for (int j = 0; j < 4; ++j)
      ctx_part[(chunk * NL + l0 + 4 * lg + j) * 512 + w * 64 + ds * 16 + lr] =
          f2bf(acc[ds][j] * sinv[j]);
}

// ---------------- K4pre: sum ctx_part chunks ---------------------------------
__global__ void k4pre(const short* __restrict__ ctx_part, short* __restrict__ ctxsum) {
  int i = blockIdx.x * blockDim.x + threadIdx.x;  // 131072 threads, 8 bf16 each
  float sm[8] = {};
#pragma unroll
  for (int c = 0; c < NCHUNK; ++c) {
    short8 v = *reinterpret_cast<const short8*>(ctx_part + (size_t)c * NL * 512 + (size_t)i * 8);
#pragma unroll
    for (int u = 0; u < 8; ++u) sm[u] += bf2f(v[u]);
  }
  short8 o;
#pragma unroll
  for (int u = 0; u < 8; ++u) o[u] = f2bf(sm[u]);
  *reinterpret_cast<short8*>(ctxsum + (size_t)i * 8) = o;
}

// ---------------- K4: ctx @ Wo^T + bo + q, LayerNorm -------------------------
__global__ void k4_out(const short* __restrict__ ctxsum, const short* __restrict__ Wob,
                       const float* __restrict__ q, const float* __restrict__ bo,
                       const float* __restrict__ gamma, const float* __restrict__ beta,
                       float* __restrict__ out) {
  __shared__ float xs[16][512];
  int lane = threadIdx.x & 63, warp = threadIdx.x >> 6;
  int lr = lane & 15, lg = lane >> 4;
  int l0 = blockIdx.x * 16;
  short8 afr[16];
#pragma unroll
  for (int kk = 0; kk < 16; ++kk)
    afr[kk] = *reinterpret_cast<const short8*>(ctxsum + (l0 + lr) * 512 + kk * 32 + 8 * lg);
#pragma unroll 1
  for (int cs = 0; cs < 8; ++cs) {
    int col0 = warp * 128 + cs * 16;
    float4v c = {};
#pragma unroll
    for (int kk = 0; kk < 16; ++kk) {
      const short* bp = Wob + (col0 + lr) * 512 + kk * 32 + 8 * lg;
      short8 b = *reinterpret_cast<const short8*>(bp);
      c = __builtin_amdgcn_mfma_f32_16x16x32_bf16(afr[kk], b, c, 0, 0, 0);
    }
#pragma unroll
    for (int j = 0; j < 4; ++j) {
      int row = l0 + 4 * lg + j, col = col0 + lr;
      xs[4 * lg + j][col] = c[j] + bo[col] + q[row * 512 + col];
    }
  }
  __syncthreads();
  int tid = threadIdx.x;
  int rl = tid >> 4, g = tid & 15;
  float sum = 0.f;
#pragma unroll
  for (int i = 0; i < 32; ++i) sum += xs[rl][g + 16 * i];
  sum += __shfl_xor(sum, 1, 64); sum += __shfl_xor(sum, 2, 64);
  sum += __shfl_xor(sum, 4, 64); sum += __shfl_xor(sum, 8, 64);
  float mu = sum * (1.0f / 512.0f);
  float vs = 0.f;
#pragma unroll
  for (int i = 0; i < 32; ++i) { float d = xs[rl][g + 16 * i] - mu; vs += d * d; }
  vs += __shfl_xor(vs, 1, 64); vs += __shfl_xor(vs, 2, 64);
  vs += __shfl_xor(vs, 4, 64); vs += __shfl_xor(vs, 8, 64);
  float rs = rsqrtf(vs * (1.0f / 512.0f) + LN_EPS);
#pragma unroll
  for (int i = 0; i < 32; ++i) {
    int cc = g + 16 * i;
    out[(l0 + rl) * 512 + cc] = (xs[rl][cc] - mu) * rs * gamma[cc] + beta[cc];
  }
}

extern "C" void kernel_launch(void* const* d_in, const int* in_sizes, int n_in,
                              void* d_out, int out_size, void* d_ws, size_t ws_size,
                              hipStream_t stream) {
  const float* q     = (const float*)d_in[0];
  const float* kv    = (const float*)d_in[1];
  const float* bias  = (const float*)d_in[2];
  const float* Wq    = (const float*)d_in[3];
  const float* Wk    = (const float*)d_in[4];
  const float* Wv    = (const float*)d_in[5];
  const float* Wo    = (const float*)d_in[6];
  const float* bo    = (const float*)d_in[7];
  const float* gamma = (const float*)d_in[8];
  const float* beta  = (const float*)d_in[9];
  float* out = (float*)d_out;
  float* attn_mean = out + (size_t)NL * 512;

  char* ws = (char*)d_ws;
  short* qb       = (short*)(ws + 0);         // 2 MB
  short* kvb      = (short*)(ws + 2097152);   // 4 MB
  short* Wqb      = (short*)(ws + 6291456);   // 512 KB
  short* Wkb      = (short*)(ws + 6815744);
  short* Wvb      = (short*)(ws + 7340032);
  short* Wob      = (short*)(ws + 7864320);
  short* Qb       = (short*)(ws + 8388608);   // 2 MB
  short* Kb       = (short*)(ws + 10485760);  // 4 MB
  short* VT       = (short*)(ws + 14680064);  // 4 MB
  float* S_part   = (float*)(ws + 18874368);  // 512 KB
  float* Sinv     = (float*)(ws + 19398656);  // 64 KB
  short* ctx_part = (short*)(ws + 19464192);  // 16 MB
  short* ctxsum   = (short*)(ws + 36241408);  // 2 MB  (total ~38.2 MB)

  k0_cvt<<<2048, 256, 0, stream>>>(q, kv, Wq, Wk, Wv, Wo, qb, kvb, Wqb, Wkb, Wvb, Wob);
  k1_proj<<<1280, 256, 0, stream>>>(qb, kvb, Wqb, Wkb, Wvb, Qb, Kb, VT);
  k2_passA<<<dim3(128, 8), 512, 0, stream>>>(Qb, Kb, bias, S_part);
  k2b_reduceS<<<64, 256, 0, stream>>>(S_part, Sinv);
  k3_passB<<<dim3(128, 8), 512, 0, stream>>>(Qb, Kb, VT, bias, Sinv, attn_mean, ctx_part);
  k4pre<<<512, 256, 0, stream>>>(ctx_part, ctxsum);
  k4_out<<<128, 256, 0, stream>>>(ctxsum, Wob, q, bo, gamma, beta, out);
}

// Round 8
// 373.809 us; speedup vs baseline: 1.4393x; 1.0005x over previous
//
#include <hip/hip_runtime.h>
#include <hip/hip_bf16.h>
#include <stdint.h>

#define NL 2048
#define NR 4096
#define NCHUNK 8
#define CHUNK (NR / NCHUNK) /* 512 */
#define SCALE 0.125f
#define LN_EPS 1e-5f

typedef __attribute__((ext_vector_type(8))) short short8;  // 8 bf16 in 4 VGPRs
typedef __attribute__((ext_vector_type(4))) float float4v;

static __device__ __forceinline__ short f2bf(float f) {
  union { float f; uint32_t u; } v; v.f = f;
  uint32_t u = v.u;
  uint32_t r = (u + 0x7FFFu + ((u >> 16) & 1u)) >> 16;  // RNE
  return (short)(r & 0xFFFFu);
}
static __device__ __forceinline__ float bf2f(short b) {
  union { uint32_t u; float f; } v; v.u = ((uint32_t)(uint16_t)b) << 16;
  return v.f;
}
// packed f32x2 -> bf16x2 (RNE), lo = a, hi = b
static __device__ __forceinline__ uint32_t cvtpk(float a, float b) {
  uint32_t r;
  asm("v_cvt_pk_bf16_f32 %0, %1, %2" : "=v"(r) : "v"(a), "v"(b));
  return r;
}

// ---------------- K0: fp32 -> bf16 conversions -------------------------------
__global__ void k0_cvt(const float* __restrict__ q, const float* __restrict__ kv,
                       const float* __restrict__ Wq, const float* __restrict__ Wk,
                       const float* __restrict__ Wv, const float* __restrict__ Wo,
                       short* __restrict__ qb, short* __restrict__ kvb,
                       short* __restrict__ Wqb, short* __restrict__ Wkb,
                       short* __restrict__ Wvb, short* __restrict__ Wob) {
  int i = blockIdx.x * blockDim.x + threadIdx.x;
  const float* src; short* dst;
  if (i < 131072)                 { src = q;  dst = qb;  }
  else if ((i -= 131072) < 262144){ src = kv; dst = kvb; }
  else if ((i -= 262144) < 32768) { src = Wq; dst = Wqb; }
  else if ((i -= 32768) < 32768)  { src = Wk; dst = Wkb; }
  else if ((i -= 32768) < 32768)  { src = Wv; dst = Wvb; }
  else { i -= 32768;                src = Wo; dst = Wob; }
  const float4* s4 = reinterpret_cast<const float4*>(src) + (size_t)i * 2;
  float4 a = s4[0], b = s4[1];
  short8 o;
  o[0] = f2bf(a.x); o[1] = f2bf(a.y); o[2] = f2bf(a.z); o[3] = f2bf(a.w);
  o[4] = f2bf(b.x); o[5] = f2bf(b.y); o[6] = f2bf(b.z); o[7] = f2bf(b.w);
  *reinterpret_cast<short8*>(dst + (size_t)i * 8) = o;
}

// ---------------- K1: projections (X @ W^T) as bf16 MFMA ---------------------
__global__ void k1_proj(const short* __restrict__ qb, const short* __restrict__ kvb,
                        const short* __restrict__ Wqb, const short* __restrict__ Wkb,
                        const short* __restrict__ Wvb,
                        short* __restrict__ Qb, short* __restrict__ Kb,
                        short* __restrict__ VT) {
  int lane = threadIdx.x & 63, warp = threadIdx.x >> 6;
  int wid = blockIdx.x * 4 + warp;
  int lr = lane & 15, lg = lane >> 4;
  const short *src, *W; short* dst; int mt, ct, mode;
  if (wid < 1024)      { src = qb;  W = Wqb; dst = Qb; mt = wid & 127; ct = wid >> 7; mode = 0; }
  else if (wid < 3072) { int id = wid - 1024; src = kvb; W = Wkb; dst = Kb; mt = id & 255; ct = id >> 8; mode = 0; }
  else                 { int id = wid - 3072; src = kvb; W = Wvb; dst = VT; mt = id & 255; ct = id >> 8; mode = 1; }
  int m0 = mt * 16, c0 = ct * 64;
  float4v acc[4] = {};
  const short* arow = src + (m0 + lr) * 512 + 8 * lg;
#pragma unroll
  for (int kk = 0; kk < 16; ++kk) {
    short8 a = *reinterpret_cast<const short8*>(arow + kk * 32);
#pragma unroll
    for (int cs = 0; cs < 4; ++cs) {
      const short* bp = W + (c0 + cs * 16 + lr) * 512 + kk * 32 + 8 * lg;
      short8 b = *reinterpret_cast<const short8*>(bp);
      acc[cs] = __builtin_amdgcn_mfma_f32_16x16x32_bf16(a, b, acc[cs], 0, 0, 0);
    }
  }
  if (mode == 0) {
#pragma unroll
    for (int cs = 0; cs < 4; ++cs)
#pragma unroll
      for (int j = 0; j < 4; ++j)
        dst[(m0 + 4 * lg + j) * 512 + c0 + cs * 16 + lr] = f2bf(acc[cs][j]);
  } else {
#pragma unroll
    for (int cs = 0; cs < 4; ++cs)
#pragma unroll
      for (int j = 0; j < 4; ++j)
        dst[(c0 + cs * 16 + lr) * 4096 + m0 + 4 * lg + j] = f2bf(acc[cs][j]);
  }
}

// ---------------- K2: pass A — per-(head,row) sum of exp(logit) --------------
// block: 8 waves over SAME 16 rows; wave w = head w. No LDS, no barriers.
// bias loads software-pipelined one iter ahead (ping-pong, no copies).
#define K2_LOADB(dst, itv)                                                    \
  {                                                                           \
    int r0n = r_base + (itv) * 32;                                            \
    _Pragma("unroll") for (int s = 0; s < 2; ++s)                             \
    _Pragma("unroll") for (int j = 0; j < 4; ++j)                             \
      dst[s][j] = bias[(l0 + 4 * lg + j) * (size_t)NR + r0n + s * 16 + lr];   \
  }
#define K2_BODY(bv, itv)                                                      \
  {                                                                           \
    int r0 = r_base + (itv) * 32;                                             \
    float4v cc[2];                                                            \
    _Pragma("unroll") for (int s = 0; s < 2; ++s) {                           \
      const short* kp = Kb + (r0 + s * 16 + lr) * 512 + w * 64 + 8 * lg;      \
      short8 b0 = *reinterpret_cast<const short8*>(kp);                       \
      short8 b1 = *reinterpret_cast<const short8*>(kp + 32);                  \
      float4v c = {};                                                         \
      c = __builtin_amdgcn_mfma_f32_16x16x32_bf16(qa0, b0, c, 0, 0, 0);       \
      c = __builtin_amdgcn_mfma_f32_16x16x32_bf16(qa1, b1, c, 0, 0, 0);       \
      cc[s] = c;                                                              \
    }                                                                         \
    _Pragma("unroll") for (int s = 0; s < 2; ++s)                             \
    _Pragma("unroll") for (int j = 0; j < 4; ++j)                             \
      sums[j] += __expf(fmaf(SCALE, cc[s][j], bv[s][j]));                     \
  }
__global__ void __launch_bounds__(512, 8)
k2_passA(const short* __restrict__ Qb, const short* __restrict__ Kb,
         const float* __restrict__ bias, float* __restrict__ S_part) {
  int lane = threadIdx.x & 63, w = threadIdx.x >> 6;  // w = head
  int lr = lane & 15, lg = lane >> 4;
  int l0 = blockIdx.x * 16;
  int chunk = blockIdx.y;
  int r_base = chunk * CHUNK;
  float sums[4] = {};
  const short* qrow = Qb + (l0 + lr) * 512 + 8 * lg;
  short8 qa0 = *reinterpret_cast<const short8*>(qrow + w * 64);
  short8 qa1 = *reinterpret_cast<const short8*>(qrow + w * 64 + 32);
  float bvA[2][4], bvB[2][4];
  K2_LOADB(bvA, 0)
#pragma unroll 1
  for (int it2 = 0; it2 < 8; ++it2) {
    K2_LOADB(bvB, 2 * it2 + 1)
    K2_BODY(bvA, 2 * it2)
    if (it2 < 7) K2_LOADB(bvA, 2 * it2 + 2)
    K2_BODY(bvB, 2 * it2 + 1)
  }
#pragma unroll
  for (int j = 0; j < 4; ++j) {
    float v = sums[j];
    v += __shfl_xor(v, 1, 64); v += __shfl_xor(v, 2, 64);
    v += __shfl_xor(v, 4, 64); v += __shfl_xor(v, 8, 64);
    sums[j] = v;
  }
  if (lr == 0) {
#pragma unroll
    for (int j = 0; j < 4; ++j)
      S_part[(chunk * 8 + w) * NL + l0 + 4 * lg + j] = sums[j];
  }
}

// ---------------- K2b: reduce S partials -> 1/S ------------------------------
__global__ void k2b_reduceS(const float* __restrict__ S_part, float* __restrict__ Sinv) {
  int i = blockIdx.x * blockDim.x + threadIdx.x;  // h*2048 + l
  int h = i >> 11, l = i & 2047;
  float s = 0.f;
#pragma unroll
  for (int c = 0; c < NCHUNK; ++c) s += S_part[(c * 8 + h) * NL + l];
  Sinv[i] = 1.0f / s;
}

// ---------------- K3: pass B — attn_mean + PV partials -----------------------
// Swapped QK (mfma(K,Q)): lane holds P for ONE q-row (q=lane&15), 8 r-values.
// P normalized (e*sinv) -> packed cvt_pk -> 2x ds_write_b64 -> ds_read_b128
// A-frag -> PV. attn_mean = head-sum of P_lds. Double-buffered P and bias
// tiles, ONE barrier per iteration.
__global__ void __launch_bounds__(512, 8)
k3_passB(const short* __restrict__ Qb, const short* __restrict__ Kb,
         const short* __restrict__ VT, const float* __restrict__ bias,
         const float* __restrict__ Sinv,
         float* __restrict__ attn_mean, short* __restrict__ ctx_part) {
  __shared__ __align__(16) short P[8][2][16][40];  // [head][buf][q][r(pad40)] 20.5KB
  __shared__ float BIAS[2][16][33];                // [buf][q][r(pad33)] 4.2KB
  int t = threadIdx.x;
  int lane = t & 63, w = t >> 6;  // w = head
  int lr = lane & 15, lg = lane >> 4;
  int l0 = blockIdx.x * 16;
  int chunk = blockIdx.y;
  int r_base = chunk * CHUNK;
  float4v acc[4] = {};  // [ds]: ctx[q=4lg+j][d=ds*16+lr], normalized
  float sinv = Sinv[w * NL + l0 + lr];  // per (head, q=lr)
  const short* qrow = Qb + (l0 + lr) * 512 + 8 * lg;
  short8 qa0 = *reinterpret_cast<const short8*>(qrow + w * 64);
  short8 qa1 = *reinterpret_cast<const short8*>(qrow + w * 64 + 32);
  int sq = t >> 5, sr = t & 31;  // staging/mean coords: q=sq, r=sr
  // prologue: stage bias tile 0
  BIAS[0][sq][sr] = bias[(l0 + sq) * (size_t)NR + r_base + sr];
  __syncthreads();
#pragma unroll 1
  for (int it = 0; it < CHUNK / 32; ++it) {
    int cb = it & 1;
    int r0 = r_base + it * 32;
    // stage next bias tile into the other buffer (no one reads it this iter)
    if (it < CHUNK / 32 - 1)
      BIAS[cb ^ 1][sq][sr] = bias[(l0 + sq) * (size_t)NR + r0 + 32 + sr];
    // QK^T swapped: A=K rows (r), B=Q rows (q) -> D[r_local=s16+4lg+j][q=lr]
#pragma unroll
    for (int s = 0; s < 2; ++s) {
      const short* kp = Kb + (r0 + s * 16 + lr) * 512 + w * 64 + 8 * lg;
      short8 b0 = *reinterpret_cast<const short8*>(kp);
      short8 b1 = *reinterpret_cast<const short8*>(kp + 32);
      float4v c = {};
      c = __builtin_amdgcn_mfma_f32_16x16x32_bf16(b0, qa0, c, 0, 0, 0);
      c = __builtin_amdgcn_mfma_f32_16x16x32_bf16(b1, qa1, c, 0, 0, 0);
      // normalized attn, packed to bf16 pairs, conflict-light b64 writes
      float e0 = __expf(fmaf(SCALE, c[0], BIAS[cb][lr][s * 16 + 4 * lg + 0])) * sinv;
      float e1 = __expf(fmaf(SCALE, c[1], BIAS[cb][lr][s * 16 + 4 * lg + 1])) * sinv;
      float e2 = __expf(fmaf(SCALE, c[2], BIAS[cb][lr][s * 16 + 4 * lg + 2])) * sinv;
      float e3 = __expf(fmaf(SCALE, c[3], BIAS[cb][lr][s * 16 + 4 * lg + 3])) * sinv;
      uint2 pk; pk.x = cvtpk(e0, e1); pk.y = cvtpk(e2, e3);
      *reinterpret_cast<uint2*>(&P[w][cb][lr][s * 16 + 4 * lg]) = pk;
    }
    // wave-private re-read as PV A-fragment: P[q=lr][r=8lg..8lg+7]
    short8 pa = *reinterpret_cast<const short8*>(&P[w][cb][lr][8 * lg]);
#pragma unroll
    for (int ds = 0; ds < 4; ++ds) {
      const short* vp = VT + (w * 64 + ds * 16 + lr) * 4096 + r0 + 8 * lg;
      short8 vb = *reinterpret_cast<const short8*>(vp);
      acc[ds] = __builtin_amdgcn_mfma_f32_16x16x32_bf16(pa, vb, acc[ds], 0, 0, 0);
    }
    __syncthreads();  // P[*][cb] complete for all heads; bias[cb^1] staged
    // attn_mean: head-sum of normalized P (same bytes PV consumed)
    {
      float v = 0.f;
#pragma unroll
      for (int hh = 0; hh < 8; ++hh) v += bf2f(P[hh][cb][sq][sr]);
      attn_mean[(size_t)(l0 + sq) * NR + r0 + sr] = v * 0.125f;
    }
  }
#pragma unroll
  for (int ds = 0; ds < 4; ++ds)
#pragma unroll
    for (int j = 0; j < 4; ++j)
      ctx_part[(chunk * NL + l0 + 4 * lg + j) * 512 + w * 64 + ds * 16 + lr] =
          f2bf(acc[ds][j]);
}

// ---------------- K4pre: sum ctx_part chunks ---------------------------------
__global__ void k4pre(const short* __restrict__ ctx_part, short* __restrict__ ctxsum) {
  int i = blockIdx.x * blockDim.x + threadIdx.x;  // 131072 threads, 8 bf16 each
  float sm[8] = {};
#pragma unroll
  for (int c = 0; c < NCHUNK; ++c) {
    short8 v = *reinterpret_cast<const short8*>(ctx_part + (size_t)c * NL * 512 + (size_t)i * 8);
#pragma unroll
    for (int u = 0; u < 8; ++u) sm[u] += bf2f(v[u]);
  }
  short8 o;
#pragma unroll
  for (int u = 0; u < 8; ++u) o[u] = f2bf(sm[u]);
  *reinterpret_cast<short8*>(ctxsum + (size_t)i * 8) = o;
}

// ---------------- K4: ctx @ Wo^T + bo + q, LayerNorm -------------------------
__global__ void k4_out(const short* __restrict__ ctxsum, const short* __restrict__ Wob,
                       const float* __restrict__ q, const float* __restrict__ bo,
                       const float* __restrict__ gamma, const float* __restrict__ beta,
                       float* __restrict__ out) {
  __shared__ float xs[16][512];
  int lane = threadIdx.x & 63, warp = threadIdx.x >> 6;
  int lr = lane & 15, lg = lane >> 4;
  int l0 = blockIdx.x * 16;
  short8 afr[16];
#pragma unroll
  for (int kk = 0; kk < 16; ++kk)
    afr[kk] = *reinterpret_cast<const short8*>(ctxsum + (l0 + lr) * 512 + kk * 32 + 8 * lg);
#pragma unroll 1
  for (int cs = 0; cs < 8; ++cs) {
    int col0 = warp * 128 + cs * 16;
    float4v c = {};
#pragma unroll
    for (int kk = 0; kk < 16; ++kk) {
      const short* bp = Wob + (col0 + lr) * 512 + kk * 32 + 8 * lg;
      short8 b = *reinterpret_cast<const short8*>(bp);
      c = __builtin_amdgcn_mfma_f32_16x16x32_bf16(afr[kk], b, c, 0, 0, 0);
    }
#pragma unroll
    for (int j = 0; j < 4; ++j) {
      int row = l0 + 4 * lg + j, col = col0 + lr;
      xs[4 * lg + j][col] = c[j] + bo[col] + q[row * 512 + col];
    }
  }
  __syncthreads();
  int tid = threadIdx.x;
  int rl = tid >> 4, g = tid & 15;
  float sum = 0.f;
#pragma unroll
  for (int i = 0; i < 32; ++i) sum += xs[rl][g + 16 * i];
  sum += __shfl_xor(sum, 1, 64); sum += __shfl_xor(sum, 2, 64);
  sum += __shfl_xor(sum, 4, 64); sum += __shfl_xor(sum, 8, 64);
  float mu = sum * (1.0f / 512.0f);
  float vs = 0.f;
#pragma unroll
  for (int i = 0; i < 32; ++i) { float d = xs[rl][g + 16 * i] - mu; vs += d * d; }
  vs += __shfl_xor(vs, 1, 64); vs += __shfl_xor(vs, 2, 64);
  vs += __shfl_xor(vs, 4, 64); vs += __shfl_xor(vs, 8, 64);
  float rs = rsqrtf(vs * (1.0f / 512.0f) + LN_EPS);
#pragma unroll
  for (int i = 0; i < 32; ++i) {
    int cc = g + 16 * i;
    out[(l0 + rl) * 512 + cc] = (xs[rl][cc] - mu) * rs * gamma[cc] + beta[cc];
  }
}

extern "C" void kernel_launch(void* const* d_in, const int* in_sizes, int n_in,
                              void* d_out, int out_size, void* d_ws, size_t ws_size,
                              hipStream_t stream) {
  const float* q     = (const float*)d_in[0];
  const float* kv    = (const float*)d_in[1];
  const float* bias  = (const float*)d_in[2];
  const float* Wq    = (const float*)d_in[3];
  const float* Wk    = (const float*)d_in[4];
  const float* Wv    = (const float*)d_in[5];
  const float* Wo    = (const float*)d_in[6];
  const float* bo    = (const float*)d_in[7];
  const float* gamma = (const float*)d_in[8];
  const float* beta  = (const float*)d_in[9];
  float* out = (float*)d_out;
  float* attn_mean = out + (size_t)NL * 512;

  char* ws = (char*)d_ws;
  short* qb       = (short*)(ws + 0);         // 2 MB
  short* kvb      = (short*)(ws + 2097152);   // 4 MB
  short* Wqb      = (short*)(ws + 6291456);   // 512 KB
  short* Wkb      = (short*)(ws + 6815744);
  short* Wvb      = (short*)(ws + 7340032);
  short* Wob      = (short*)(ws + 7864320);
  short* Qb       = (short*)(ws + 8388608);   // 2 MB
  short* Kb       = (short*)(ws + 10485760);  // 4 MB
  short* VT       = (short*)(ws + 14680064);  // 4 MB
  float* S_part   = (float*)(ws + 18874368);  // 512 KB
  float* Sinv     = (float*)(ws + 19398656);  // 64 KB
  short* ctx_part = (short*)(ws + 19464192);  // 16 MB
  short* ctxsum   = (short*)(ws + 36241408);  // 2 MB  (total ~38.2 MB)

  k0_cvt<<<2048, 256, 0, stream>>>(q, kv, Wq, Wk, Wv, Wo, qb, kvb, Wqb, Wkb, Wvb, Wob);
  k1_proj<<<1280, 256, 0, stream>>>(qb, kvb, Wqb, Wkb, Wvb, Qb, Kb, VT);
  k2_passA<<<dim3(128, 8), 512, 0, stream>>>(Qb, Kb, bias, S_part);
  k2b_reduceS<<<64, 256, 0, stream>>>(S_part, Sinv);
  k3_passB<<<dim3(128, 8), 512, 0, stream>>>(Qb, Kb, VT, bias, Sinv, attn_mean, ctx_part);
  k4pre<<<512, 256, 0, stream>>>(ctx_part, ctxsum);
  k4_out<<<128, 256, 0, stream>>>(ctxsum, Wob, q, bo, gamma, beta, out);
}